// Round 2
// baseline (159.596 us; speedup 1.0000x reference)
//
#include <hip/hip_runtime.h>
#include <hip/hip_bf16.h>

typedef __attribute__((ext_vector_type(8))) short short8;  // 8 bf16 (4 VGPRs)
typedef __attribute__((ext_vector_type(4))) float f32x4;

#define INF_BITS 0x7F800000u

// ---------------------------------------------------------------------------
// prep: fp32 -> bf16 conversion, exact fp32 row norms, init min arrays to +inf
// ---------------------------------------------------------------------------
__global__ __launch_bounds__(256) void ahd_prep(
    const float* __restrict__ s1, const float* __restrict__ s2,
    __hip_bfloat16* __restrict__ abf, __hip_bfloat16* __restrict__ bbf,
    float* __restrict__ x2, float* __restrict__ y2,
    unsigned int* __restrict__ rmin, unsigned int* __restrict__ cmin,
    int N, int M)
{
    const int tid  = threadIdx.x;
    const int lane = tid & 63;
    const int w    = tid >> 6;

    const int t = blockIdx.x * 256 + tid;
    if (t < N)          rmin[t]     = INF_BITS;
    else if (t < N + M) cmin[t - N] = INF_BITS;

    const int gw = blockIdx.x * 4 + w;   // global wave index == row index
    if (gw < N) {
        float v = s1[(size_t)gw * 64 + lane];
        abf[(size_t)gw * 64 + lane] = __float2bfloat16(v);
        float ss = v * v;
        #pragma unroll
        for (int s = 1; s < 64; s <<= 1) ss += __shfl_xor(ss, s);
        if (lane == 0) x2[gw] = ss;
    } else if (gw < N + M) {
        const int r = gw - N;
        float v = s2[(size_t)r * 64 + lane];
        bbf[(size_t)r * 64 + lane] = __float2bfloat16(v);
        float ss = v * v;
        #pragma unroll
        for (int s = 1; s < 64; s <<= 1) ss += __shfl_xor(ss, s);
        if (lane == 0) y2[r] = ss;
    }
}

// ---------------------------------------------------------------------------
// fused distance-GEMM + row/col min.
// Block: 128 rows x 1024 cols (8 col-tiles of 128, B double-buffered in LDS).
// 4 waves, each wave = 128 rows x 32 cols (m-frags 8, n-frags 2, 16x16x32).
// A staged once; A-frags cached in registers; rowm persists in registers.
// ---------------------------------------------------------------------------
__global__ __launch_bounds__(256) void ahd_gemm(
    const __hip_bfloat16* __restrict__ abf, const __hip_bfloat16* __restrict__ bbf,
    const float* __restrict__ x2, const float* __restrict__ y2,
    unsigned int* __restrict__ rmin, unsigned int* __restrict__ cmin,
    int NRB, int nwg)
{
    __shared__ __attribute__((aligned(128))) char ldsA[16384];
    __shared__ __attribute__((aligned(128))) char ldsB[2][16384];
    __shared__ float        ldsX[128];
    __shared__ unsigned int lrow[128];

    const int tid  = threadIdx.x;
    const int lane = tid & 63;
    const int w    = tid >> 6;
    const int lr   = lane & 15, lh = lane >> 4;

    // XCD-bijective swizzle (nwg % 8 == 0): each XCD owns 2 full col-strips
    const int bid = blockIdx.x;
    const int swz = (bid & 7) * (nwg >> 3) + (bid >> 3);
    const int brow  = (swz % NRB) * 128;
    const int bcol0 = (swz / NRB) * 1024;

    // ---- stage A tile (16 KB) + B tile 0; linear LDS dest, swizzled source
    const char* aT = (const char*)abf + (size_t)brow * 128;
    #pragma unroll
    for (int it = 0; it < 4; ++it) {
        const int dst = w * 1024 + it * 4096;
        const int o   = dst + lane * 16;
        const int so  = o ^ ((o >> 3) & 0x70);
        __builtin_amdgcn_global_load_lds(
            (const __attribute__((address_space(1))) void*)(aT + so),
            (__attribute__((address_space(3))) void*)(ldsA + dst), 16, 0, 0);
    }
    {
        const char* bT = (const char*)bbf + (size_t)bcol0 * 128;
        #pragma unroll
        for (int it = 0; it < 4; ++it) {
            const int dst = w * 1024 + it * 4096;
            const int o   = dst + lane * 16;
            const int so  = o ^ ((o >> 3) & 0x70);
            __builtin_amdgcn_global_load_lds(
                (const __attribute__((address_space(1))) void*)(bT + so),
                (__attribute__((address_space(3))) void*)(&ldsB[0][0] + dst), 16, 0, 0);
        }
    }
    if (tid < 128) { ldsX[tid] = x2[brow + tid]; lrow[tid] = INF_BITS; }

    __syncthreads();   // drains staging loads

    // ---- cache A fragments in registers (reused for all 8 col-tiles)
    short8 afr[2][8];
    #pragma unroll
    for (int ks = 0; ks < 2; ++ks)
        #pragma unroll
        for (int m = 0; m < 8; ++m) {
            int o = (m * 16 + lr) * 128 + ks * 64 + lh * 16;
            o ^= (o >> 3) & 0x70;
            afr[ks][m] = *(const short8*)(ldsA + o);
        }

    float rowm[8][4];
    #pragma unroll
    for (int m = 0; m < 8; ++m)
        #pragma unroll
        for (int j = 0; j < 4; ++j) rowm[m][j] = 1e30f;

    for (int ct = 0; ct < 8; ++ct) {
        const int cur = ct & 1;

        // prefetch next B tile into the other buffer (async, drains at barrier)
        if (ct < 7) {
            const char* bT = (const char*)bbf + (size_t)(bcol0 + (ct + 1) * 128) * 128;
            #pragma unroll
            for (int it = 0; it < 4; ++it) {
                const int dst = w * 1024 + it * 4096;
                const int o   = dst + lane * 16;
                const int so  = o ^ ((o >> 3) & 0x70);
                __builtin_amdgcn_global_load_lds(
                    (const __attribute__((address_space(1))) void*)(bT + so),
                    (__attribute__((address_space(3))) void*)(&ldsB[cur ^ 1][0] + dst), 16, 0, 0);
            }
        }

        // ---- MFMA: 2 ksteps x (8m x 2n); acc init folded into first MFMA
        f32x4 acc[8][2];
        #pragma unroll
        for (int ks = 0; ks < 2; ++ks) {
            short8 bfr[2];
            #pragma unroll
            for (int n = 0; n < 2; ++n) {
                int o = (w * 32 + n * 16 + lr) * 128 + ks * 64 + lh * 16;
                o ^= (o >> 3) & 0x70;
                bfr[n] = *(const short8*)(&ldsB[cur][0] + o);
            }
            #pragma unroll
            for (int m = 0; m < 8; ++m)
                #pragma unroll
                for (int n = 0; n < 2; ++n) {
                    f32x4 c = (ks == 0) ? (f32x4){0.f, 0.f, 0.f, 0.f} : acc[m][n];
                    acc[m][n] = __builtin_amdgcn_mfma_f32_16x16x32_bf16(
                                    afr[ks][m], bfr[n], c, 0, 0, 0);
                }
        }

        // ---- epilogue: u = y2 - 2a feeds row-min (x2 added at the end);
        //                v = x2 - 2a feeds col-min (y2 added at flush).
        const int colbase = bcol0 + ct * 128 + w * 32 + lr;
        const float yv0 = y2[colbase];
        const float yv1 = y2[colbase + 16];
        float colm0 = 1e30f, colm1 = 1e30f;
        #pragma unroll
        for (int m = 0; m < 8; ++m) {
            #pragma unroll
            for (int j = 0; j < 4; ++j) {
                const float xvv = ldsX[m * 16 + lh * 4 + j];
                const float a0 = acc[m][0][j], a1 = acc[m][1][j];
                const float u0 = fmaf(-2.f, a0, yv0);
                const float u1 = fmaf(-2.f, a1, yv1);
                rowm[m][j] = fminf(rowm[m][j], fminf(u0, u1));
                colm0 = fminf(colm0, fmaf(-2.f, a0, xvv));
                colm1 = fminf(colm1, fmaf(-2.f, a1, xvv));
            }
        }
        // col-min: combine across the 4 lh row-groups (whole column in-wave)
        colm0 = fminf(colm0, __shfl_xor(colm0, 16));
        colm0 = fminf(colm0, __shfl_xor(colm0, 32));
        colm1 = fminf(colm1, __shfl_xor(colm1, 16));
        colm1 = fminf(colm1, __shfl_xor(colm1, 32));
        if (lh == 0) {
            const float d0 = fmaxf(colm0 + yv0, 0.f);
            const float d1 = fmaxf(colm1 + yv1, 0.f);
            atomicMin(&cmin[colbase],      __float_as_uint(d0));
            atomicMin(&cmin[colbase + 16], __float_as_uint(d1));
        }

        __syncthreads();   // all reads of ldsB[cur] done; prefetch drained
    }

    // ---- row-min: cross-lane (lr) reduce once per block, then cross-wave LDS
    #pragma unroll
    for (int m = 0; m < 8; ++m)
        #pragma unroll
        for (int j = 0; j < 4; ++j) {
            float v = rowm[m][j];
            v = fminf(v, __shfl_xor(v, 1));
            v = fminf(v, __shfl_xor(v, 2));
            v = fminf(v, __shfl_xor(v, 4));
            v = fminf(v, __shfl_xor(v, 8));
            if (lr == 0) {
                const int row = m * 16 + lh * 4 + j;
                const float d2 = fmaxf(ldsX[row] + v, 0.f);
                atomicMin(&lrow[row], __float_as_uint(d2));
            }
        }
    __syncthreads();
    if (tid < 128) atomicMin(&rmin[brow + tid], lrow[tid]);
}

// ---------------------------------------------------------------------------
// finalize: out = mean(sqrt(rmin)) + mean(sqrt(cmin)); 1024 thr, uint4 loads.
// ---------------------------------------------------------------------------
__global__ __launch_bounds__(1024) void ahd_finalize(
    const unsigned int* __restrict__ rmin, const unsigned int* __restrict__ cmin,
    float* __restrict__ out, int N, int M)
{
    const int tid = threadIdx.x;
    const uint4* r4 = (const uint4*)rmin;
    const uint4* c4 = (const uint4*)cmin;
    float sa = 0.f, sb = 0.f;
    for (int i = tid; i < (N >> 2); i += 1024) {
        const uint4 v = r4[i];
        sa += sqrtf(__uint_as_float(v.x)) + sqrtf(__uint_as_float(v.y))
            + sqrtf(__uint_as_float(v.z)) + sqrtf(__uint_as_float(v.w));
    }
    for (int i = tid; i < (M >> 2); i += 1024) {
        const uint4 v = c4[i];
        sb += sqrtf(__uint_as_float(v.x)) + sqrtf(__uint_as_float(v.y))
            + sqrtf(__uint_as_float(v.z)) + sqrtf(__uint_as_float(v.w));
    }
    float v = sa / (float)N + sb / (float)M;
    #pragma unroll
    for (int s = 1; s < 64; s <<= 1) v += __shfl_xor(v, s);
    __shared__ float red[16];
    if ((tid & 63) == 0) red[tid >> 6] = v;
    __syncthreads();
    if (tid == 0) {
        float t = 0.f;
        #pragma unroll
        for (int i = 0; i < 16; ++i) t += red[i];
        out[0] = t;
    }
}

extern "C" void kernel_launch(void* const* d_in, const int* in_sizes, int n_in,
                              void* d_out, int out_size, void* d_ws, size_t ws_size,
                              hipStream_t stream) {
    const float* s1 = (const float*)d_in[0];
    const float* s2 = (const float*)d_in[1];
    const int N = in_sizes[0] / 64;
    const int M = in_sizes[1] / 64;

    char* ws = (char*)d_ws;
    __hip_bfloat16* abf = (__hip_bfloat16*)ws;
    __hip_bfloat16* bbf = (__hip_bfloat16*)(ws + (size_t)N * 128);
    float* x2 = (float*)(ws + (size_t)(N + M) * 128);
    float* y2 = x2 + N;
    unsigned int* rmin = (unsigned int*)(y2 + M);
    unsigned int* cmin = rmin + N;

    const int rows = N + M;
    ahd_prep<<<(rows + 3) / 4, 256, 0, stream>>>(s1, s2, abf, bbf, x2, y2,
                                                 rmin, cmin, N, M);
    const int NRB = N / 128;            // 128 row-blocks
    const int STRIPS = M / 1024;        // 16 col-strips
    const int nwg = NRB * STRIPS;       // 2048 blocks
    ahd_gemm<<<nwg, 256, 0, stream>>>(abf, bbf, x2, y2, rmin, cmin, NRB, nwg);
    ahd_finalize<<<1, 1024, 0, stream>>>(rmin, cmin, (float*)d_out, N, M);
}

// Round 3
// 157.192 us; speedup vs baseline: 1.0153x; 1.0153x over previous
//
#include <hip/hip_runtime.h>
#include <hip/hip_bf16.h>

typedef __attribute__((ext_vector_type(8))) short short8;  // 8 bf16 (4 VGPRs)
typedef __attribute__((ext_vector_type(4))) float f32x4;

#define INF_BITS 0x7F800000u

// ---------------------------------------------------------------------------
// prep: fp32 -> bf16 conversion, exact fp32 row norms, init min arrays to +inf
// ---------------------------------------------------------------------------
__global__ __launch_bounds__(256) void ahd_prep(
    const float* __restrict__ s1, const float* __restrict__ s2,
    __hip_bfloat16* __restrict__ abf, __hip_bfloat16* __restrict__ bbf,
    float* __restrict__ x2, float* __restrict__ y2,
    unsigned int* __restrict__ rmin, unsigned int* __restrict__ cmin,
    int N, int M)
{
    const int tid  = threadIdx.x;
    const int lane = tid & 63;
    const int w    = tid >> 6;

    const int t = blockIdx.x * 256 + tid;
    if (t < N)          rmin[t]     = INF_BITS;
    else if (t < N + M) cmin[t - N] = INF_BITS;

    const int gw = blockIdx.x * 4 + w;   // global wave index == row index
    if (gw < N) {
        float v = s1[(size_t)gw * 64 + lane];
        abf[(size_t)gw * 64 + lane] = __float2bfloat16(v);
        float ss = v * v;
        #pragma unroll
        for (int s = 1; s < 64; s <<= 1) ss += __shfl_xor(ss, s);
        if (lane == 0) x2[gw] = ss;
    } else if (gw < N + M) {
        const int r = gw - N;
        float v = s2[(size_t)r * 64 + lane];
        bbf[(size_t)r * 64 + lane] = __float2bfloat16(v);
        float ss = v * v;
        #pragma unroll
        for (int s = 1; s < 64; s <<= 1) ss += __shfl_xor(ss, s);
        if (lane == 0) y2[r] = ss;
    }
}

// ---------------------------------------------------------------------------
// fused distance-GEMM + row/col min.
// Block: 128 rows x 1024 cols (8 col-tiles of 128, B double-buffered in LDS).
// 4 waves, each wave = 128 rows x 32 cols (m-frags 8, n-frags 2, 16x16x32).
// A staged once; A-frags cached in registers; rowm persists in registers.
// Col-mins go to LDS colbuf per-iteration (plain writes); ALL global atomics
// happen fire-and-forget at block end — nothing contended inside the
// barrier-synced loop (round-2 lesson: in-loop atomics + vmcnt drain = stall).
// ---------------------------------------------------------------------------
__global__ __launch_bounds__(256) void ahd_gemm(
    const __hip_bfloat16* __restrict__ abf, const __hip_bfloat16* __restrict__ bbf,
    const float* __restrict__ x2, const float* __restrict__ y2,
    unsigned int* __restrict__ rmin, unsigned int* __restrict__ cmin,
    int NRB, int nwg)
{
    __shared__ __attribute__((aligned(128))) char ldsA[16384];
    __shared__ __attribute__((aligned(128))) char ldsB[2][16384];
    __shared__ __attribute__((aligned(16)))  float ldsX[128];
    __shared__ float        colbuf[1024];
    __shared__ unsigned int lrow[128];

    const int tid  = threadIdx.x;
    const int lane = tid & 63;
    const int w    = tid >> 6;
    const int lr   = lane & 15, lh = lane >> 4;

    // XCD-bijective swizzle (nwg % 8 == 0): each XCD owns 2 full col-strips
    const int bid = blockIdx.x;
    const int swz = (bid & 7) * (nwg >> 3) + (bid >> 3);
    const int brow  = (swz % NRB) * 128;
    const int bcol0 = (swz / NRB) * 1024;

    // ---- stage A tile (16 KB) + B tile 0; linear LDS dest, swizzled source
    const char* aT = (const char*)abf + (size_t)brow * 128;
    #pragma unroll
    for (int it = 0; it < 4; ++it) {
        const int dst = w * 1024 + it * 4096;
        const int o   = dst + lane * 16;
        const int so  = o ^ ((o >> 3) & 0x70);
        __builtin_amdgcn_global_load_lds(
            (const __attribute__((address_space(1))) void*)(aT + so),
            (__attribute__((address_space(3))) void*)(ldsA + dst), 16, 0, 0);
    }
    {
        const char* bT = (const char*)bbf + (size_t)bcol0 * 128;
        #pragma unroll
        for (int it = 0; it < 4; ++it) {
            const int dst = w * 1024 + it * 4096;
            const int o   = dst + lane * 16;
            const int so  = o ^ ((o >> 3) & 0x70);
            __builtin_amdgcn_global_load_lds(
                (const __attribute__((address_space(1))) void*)(bT + so),
                (__attribute__((address_space(3))) void*)(&ldsB[0][0] + dst), 16, 0, 0);
        }
    }
    if (tid < 128) { ldsX[tid] = x2[brow + tid]; lrow[tid] = INF_BITS; }

    __syncthreads();   // drains staging loads

    // ---- cache A fragments in registers (reused for all 8 col-tiles)
    short8 afr[2][8];
    #pragma unroll
    for (int ks = 0; ks < 2; ++ks)
        #pragma unroll
        for (int m = 0; m < 8; ++m) {
            int o = (m * 16 + lr) * 128 + ks * 64 + lh * 16;
            o ^= (o >> 3) & 0x70;
            afr[ks][m] = *(const short8*)(ldsA + o);
        }

    float rowm[8][4];
    #pragma unroll
    for (int m = 0; m < 8; ++m)
        #pragma unroll
        for (int j = 0; j < 4; ++j) rowm[m][j] = 1e30f;

    for (int ct = 0; ct < 8; ++ct) {
        const int cur = ct & 1;

        // prefetch next B tile into the other buffer (async, drains at barrier)
        if (ct < 7) {
            const char* bT = (const char*)bbf + (size_t)(bcol0 + (ct + 1) * 128) * 128;
            #pragma unroll
            for (int it = 0; it < 4; ++it) {
                const int dst = w * 1024 + it * 4096;
                const int o   = dst + lane * 16;
                const int so  = o ^ ((o >> 3) & 0x70);
                __builtin_amdgcn_global_load_lds(
                    (const __attribute__((address_space(1))) void*)(bT + so),
                    (__attribute__((address_space(3))) void*)(&ldsB[cur ^ 1][0] + dst), 16, 0, 0);
            }
        }

        // ---- MFMA: 2 ksteps x (8m x 2n); acc init folded into first MFMA
        f32x4 acc[8][2];
        #pragma unroll
        for (int ks = 0; ks < 2; ++ks) {
            short8 bfr[2];
            #pragma unroll
            for (int n = 0; n < 2; ++n) {
                int o = (w * 32 + n * 16 + lr) * 128 + ks * 64 + lh * 16;
                o ^= (o >> 3) & 0x70;
                bfr[n] = *(const short8*)(&ldsB[cur][0] + o);
            }
            #pragma unroll
            for (int m = 0; m < 8; ++m)
                #pragma unroll
                for (int n = 0; n < 2; ++n) {
                    f32x4 c = (ks == 0) ? (f32x4){0.f, 0.f, 0.f, 0.f} : acc[m][n];
                    acc[m][n] = __builtin_amdgcn_mfma_f32_16x16x32_bf16(
                                    afr[ks][m], bfr[n], c, 0, 0, 0);
                }
        }

        // ---- epilogue: rowm tracks min(y2 - 2a); col path tracks min(x2 - 2a)
        const int colbase = bcol0 + ct * 128 + w * 32 + lr;
        const float yv0 = y2[colbase];
        const float yv1 = y2[colbase + 16];
        float colm0 = 1e30f, colm1 = 1e30f;
        #pragma unroll
        for (int m = 0; m < 8; ++m) {
            const f32x4 xq = *(const f32x4*)&ldsX[m * 16 + lh * 4]; // broadcast b128
            #pragma unroll
            for (int j = 0; j < 4; ++j) {
                const float a0 = acc[m][0][j], a1 = acc[m][1][j];
                const float u0 = fmaf(-2.f, a0, yv0);
                const float u1 = fmaf(-2.f, a1, yv1);
                rowm[m][j] = fminf(rowm[m][j], fminf(u0, u1));
                colm0 = fminf(colm0, fmaf(-2.f, a0, xq[j]));
                colm1 = fminf(colm1, fmaf(-2.f, a1, xq[j]));
            }
        }
        // col-min: combine across the 4 lh row-groups, store to LDS (no atomics)
        colm0 = fminf(colm0, __shfl_xor(colm0, 16));
        colm0 = fminf(colm0, __shfl_xor(colm0, 32));
        colm1 = fminf(colm1, __shfl_xor(colm1, 16));
        colm1 = fminf(colm1, __shfl_xor(colm1, 32));
        if (lh == 0) {
            colbuf[ct * 128 + w * 32 + lr]      = colm0;
            colbuf[ct * 128 + w * 32 + lr + 16] = colm1;
        }

        __syncthreads();   // all reads of ldsB[cur] done; prefetch drained
    }

    // ---- row-min: cross-lane (lr) reduce once per block, then cross-wave LDS
    #pragma unroll
    for (int m = 0; m < 8; ++m)
        #pragma unroll
        for (int j = 0; j < 4; ++j) {
            float v = rowm[m][j];
            v = fminf(v, __shfl_xor(v, 1));
            v = fminf(v, __shfl_xor(v, 2));
            v = fminf(v, __shfl_xor(v, 4));
            v = fminf(v, __shfl_xor(v, 8));
            if (lr == 0) {
                const int row = m * 16 + lh * 4 + j;
                const float d2 = fmaxf(ldsX[row] + v, 0.f);
                atomicMin(&lrow[row], __float_as_uint(d2));   // LDS atomic, cheap
            }
        }
    __syncthreads();

    // ---- flush: fire-and-forget global atomics AFTER the last barrier
    if (tid < 128) atomicMin(&rmin[brow + tid], lrow[tid]);
    {
        const f32x4 cv = *(const f32x4*)&colbuf[tid * 4];
        const float4 yq = *(const float4*)&y2[bcol0 + tid * 4];
        const float d0 = fmaxf(cv[0] + yq.x, 0.f);
        const float d1 = fmaxf(cv[1] + yq.y, 0.f);
        const float d2 = fmaxf(cv[2] + yq.z, 0.f);
        const float d3 = fmaxf(cv[3] + yq.w, 0.f);
        atomicMin(&cmin[bcol0 + tid * 4 + 0], __float_as_uint(d0));
        atomicMin(&cmin[bcol0 + tid * 4 + 1], __float_as_uint(d1));
        atomicMin(&cmin[bcol0 + tid * 4 + 2], __float_as_uint(d2));
        atomicMin(&cmin[bcol0 + tid * 4 + 3], __float_as_uint(d3));
    }
}

// ---------------------------------------------------------------------------
// finalize: out = mean(sqrt(rmin)) + mean(sqrt(cmin)); 1024 thr, uint4 loads.
// ---------------------------------------------------------------------------
__global__ __launch_bounds__(1024) void ahd_finalize(
    const unsigned int* __restrict__ rmin, const unsigned int* __restrict__ cmin,
    float* __restrict__ out, int N, int M)
{
    const int tid = threadIdx.x;
    const uint4* r4 = (const uint4*)rmin;
    const uint4* c4 = (const uint4*)cmin;
    float sa = 0.f, sb = 0.f;
    for (int i = tid; i < (N >> 2); i += 1024) {
        const uint4 v = r4[i];
        sa += sqrtf(__uint_as_float(v.x)) + sqrtf(__uint_as_float(v.y))
            + sqrtf(__uint_as_float(v.z)) + sqrtf(__uint_as_float(v.w));
    }
    for (int i = tid; i < (M >> 2); i += 1024) {
        const uint4 v = c4[i];
        sb += sqrtf(__uint_as_float(v.x)) + sqrtf(__uint_as_float(v.y))
            + sqrtf(__uint_as_float(v.z)) + sqrtf(__uint_as_float(v.w));
    }
    float v = sa / (float)N + sb / (float)M;
    #pragma unroll
    for (int s = 1; s < 64; s <<= 1) v += __shfl_xor(v, s);
    __shared__ float red[16];
    if ((tid & 63) == 0) red[tid >> 6] = v;
    __syncthreads();
    if (tid == 0) {
        float t = 0.f;
        #pragma unroll
        for (int i = 0; i < 16; ++i) t += red[i];
        out[0] = t;
    }
}

extern "C" void kernel_launch(void* const* d_in, const int* in_sizes, int n_in,
                              void* d_out, int out_size, void* d_ws, size_t ws_size,
                              hipStream_t stream) {
    const float* s1 = (const float*)d_in[0];
    const float* s2 = (const float*)d_in[1];
    const int N = in_sizes[0] / 64;
    const int M = in_sizes[1] / 64;

    char* ws = (char*)d_ws;
    __hip_bfloat16* abf = (__hip_bfloat16*)ws;
    __hip_bfloat16* bbf = (__hip_bfloat16*)(ws + (size_t)N * 128);
    float* x2 = (float*)(ws + (size_t)(N + M) * 128);
    float* y2 = x2 + N;
    unsigned int* rmin = (unsigned int*)(y2 + M);
    unsigned int* cmin = rmin + N;

    const int rows = N + M;
    ahd_prep<<<(rows + 3) / 4, 256, 0, stream>>>(s1, s2, abf, bbf, x2, y2,
                                                 rmin, cmin, N, M);
    const int NRB = N / 128;            // 128 row-blocks
    const int STRIPS = M / 1024;        // 16 col-strips
    const int nwg = NRB * STRIPS;       // 2048 blocks
    ahd_gemm<<<nwg, 256, 0, stream>>>(abf, bbf, x2, y2, rmin, cmin, NRB, nwg);
    ahd_finalize<<<1, 1024, 0, stream>>>(rmin, cmin, (float*)d_out, N, M);
}

// Round 4
// 142.053 us; speedup vs baseline: 1.1235x; 1.1066x over previous
//
#include <hip/hip_runtime.h>
#include <hip/hip_bf16.h>

typedef __attribute__((ext_vector_type(8))) short short8;  // 8 bf16 (4 VGPRs)
typedef __attribute__((ext_vector_type(4))) float f32x4;
typedef __attribute__((ext_vector_type(2))) float f32x2;

#define INF_BITS 0x7F800000u

// ---------------------------------------------------------------------------
// prep: fp32 -> bf16 conversion, exact fp32 row norms, init min arrays to +inf
// ---------------------------------------------------------------------------
__global__ __launch_bounds__(256) void ahd_prep(
    const float* __restrict__ s1, const float* __restrict__ s2,
    __hip_bfloat16* __restrict__ abf, __hip_bfloat16* __restrict__ bbf,
    float* __restrict__ x2, float* __restrict__ y2,
    unsigned int* __restrict__ rmin, unsigned int* __restrict__ cmin,
    int N, int M)
{
    const int tid  = threadIdx.x;
    const int lane = tid & 63;
    const int w    = tid >> 6;

    const int t = blockIdx.x * 256 + tid;
    if (t < N)          rmin[t]     = INF_BITS;
    else if (t < N + M) cmin[t - N] = INF_BITS;

    const int gw = blockIdx.x * 4 + w;   // global wave index == row index
    if (gw < N) {
        float v = s1[(size_t)gw * 64 + lane];
        abf[(size_t)gw * 64 + lane] = __float2bfloat16(v);
        float ss = v * v;
        #pragma unroll
        for (int s = 1; s < 64; s <<= 1) ss += __shfl_xor(ss, s);
        if (lane == 0) x2[gw] = ss;
    } else if (gw < N + M) {
        const int r = gw - N;
        float v = s2[(size_t)r * 64 + lane];
        bbf[(size_t)r * 64 + lane] = __float2bfloat16(v);
        float ss = v * v;
        #pragma unroll
        for (int s = 1; s < 64; s <<= 1) ss += __shfl_xor(ss, s);
        if (lane == 0) y2[r] = ss;
    }
}

// ---------------------------------------------------------------------------
// fused distance-GEMM + row/col min.
// Block: 128 rows x 1024 cols. A staged to LDS once (single prologue barrier);
// B fragments loaded global->reg (L2-hot, shared per XCD), software-pipelined
// one col-tile ahead. NO barriers in the main loop -- waves run independently
// (round-3 lesson: barrier-locked loop at 2 blocks/CU = latency-bound, both
// pipes <30% busy). Epilogue in f32x2 packed ops (v_pk_fma/min candidates).
// ---------------------------------------------------------------------------
__global__ __launch_bounds__(256) void ahd_gemm(
    const __hip_bfloat16* __restrict__ abf, const __hip_bfloat16* __restrict__ bbf,
    const float* __restrict__ x2, const float* __restrict__ y2,
    unsigned int* __restrict__ rmin, unsigned int* __restrict__ cmin,
    int NRB, int nwg)
{
    __shared__ __attribute__((aligned(128))) char ldsA[16384];
    __shared__ __attribute__((aligned(16)))  float ldsX[128];
    __shared__ float        colbuf[1024];
    __shared__ unsigned int lrow[128];

    const int tid  = threadIdx.x;
    const int lane = tid & 63;
    const int w    = tid >> 6;
    const int lr   = lane & 15, lh = lane >> 4;

    // XCD-bijective swizzle (nwg % 8 == 0): each XCD owns 2 full col-strips
    const int bid = blockIdx.x;
    const int swz = (bid & 7) * (nwg >> 3) + (bid >> 3);
    const int brow  = (swz % NRB) * 128;
    const int bcol0 = (swz / NRB) * 1024;

    // ---- stage A tile (16 KB) once; linear LDS dest, swizzled source
    const char* aT = (const char*)abf + (size_t)brow * 128;
    #pragma unroll
    for (int it = 0; it < 4; ++it) {
        const int dst = w * 1024 + it * 4096;
        const int o   = dst + lane * 16;
        const int so  = o ^ ((o >> 3) & 0x70);
        __builtin_amdgcn_global_load_lds(
            (const __attribute__((address_space(1))) void*)(aT + so),
            (__attribute__((address_space(3))) void*)(ldsA + dst), 16, 0, 0);
    }
    if (tid < 128) { ldsX[tid] = x2[brow + tid]; lrow[tid] = INF_BITS; }

    __syncthreads();   // the ONLY barrier before the flush

    // ---- cache A fragments in registers (reused for all 8 col-tiles)
    short8 afr[2][8];
    #pragma unroll
    for (int ks = 0; ks < 2; ++ks)
        #pragma unroll
        for (int m = 0; m < 8; ++m) {
            int o = (m * 16 + lr) * 128 + ks * 64 + lh * 16;
            o ^= (o >> 3) & 0x70;
            afr[ks][m] = *(const short8*)(ldsA + o);
        }

    float rowm[8][4];
    #pragma unroll
    for (int m = 0; m < 8; ++m)
        #pragma unroll
        for (int j = 0; j < 4; ++j) rowm[m][j] = 1e30f;

    // per-lane B base: col = bcol0 + w*32 + lr; frag q=(ks,n) at +n*2048+ks*64
    const char* bbase = (const char*)bbf
                      + ((size_t)(bcol0 + w * 32 + lr) * 128) + lh * 16;
    const int   col0  = bcol0 + w * 32 + lr;

    short8 bcur[4];
    #pragma unroll
    for (int q = 0; q < 4; ++q)
        bcur[q] = *(const short8*)(bbase + (q & 1) * 2048 + (q >> 1) * 64);
    float yv0 = y2[col0];
    float yv1 = y2[col0 + 16];

    #pragma unroll 2
    for (int ct = 0; ct < 8; ++ct) {
        // ---- prefetch next B fragments + y2 into regs (consumed next iter)
        short8 bnxt[4];
        float yn0 = 0.f, yn1 = 0.f;
        if (ct < 7) {
            const char* bt = bbase + (size_t)(ct + 1) * 16384;
            #pragma unroll
            for (int q = 0; q < 4; ++q)
                bnxt[q] = *(const short8*)(bt + (q & 1) * 2048 + (q >> 1) * 64);
            yn0 = y2[col0 + (ct + 1) * 128];
            yn1 = y2[col0 + (ct + 1) * 128 + 16];
        }

        // ---- MFMA: 2 ksteps x (8m x 2n); acc init folded into first MFMA
        f32x4 acc[8][2];
        #pragma unroll
        for (int ks = 0; ks < 2; ++ks)
            #pragma unroll
            for (int m = 0; m < 8; ++m)
                #pragma unroll
                for (int n = 0; n < 2; ++n) {
                    f32x4 c = (ks == 0) ? (f32x4){0.f, 0.f, 0.f, 0.f} : acc[m][n];
                    acc[m][n] = __builtin_amdgcn_mfma_f32_16x16x32_bf16(
                                    afr[ks][m], bcur[ks * 2 + n], c, 0, 0, 0);
                }

        // ---- epilogue (packed f32x2 over the two n-columns)
        const f32x2 mm2 = {-2.f, -2.f};
        const f32x2 yvv = {yv0, yv1};
        f32x2 colm = {1e30f, 1e30f};
        #pragma unroll
        for (int m = 0; m < 8; ++m) {
            const f32x4 xq = *(const f32x4*)&ldsX[m * 16 + lh * 4]; // broadcast
            #pragma unroll
            for (int j = 0; j < 4; ++j) {
                const f32x2 a = {acc[m][0][j], acc[m][1][j]};
                const f32x2 u = __builtin_elementwise_fma(mm2, a, yvv);
                rowm[m][j] = fminf(rowm[m][j], fminf(u.x, u.y));
                const f32x2 xx = {xq[j], xq[j]};
                colm = __builtin_elementwise_min(
                           colm, __builtin_elementwise_fma(mm2, a, xx));
            }
        }
        // col-min: combine across the 4 lh row-groups, store to LDS (raceless:
        // indices are exclusive per wave; read only after the final barrier)
        colm.x = fminf(colm.x, __shfl_xor(colm.x, 16));
        colm.x = fminf(colm.x, __shfl_xor(colm.x, 32));
        colm.y = fminf(colm.y, __shfl_xor(colm.y, 16));
        colm.y = fminf(colm.y, __shfl_xor(colm.y, 32));
        if (lh == 0) {
            colbuf[ct * 128 + w * 32 + lr]      = colm.x;
            colbuf[ct * 128 + w * 32 + lr + 16] = colm.y;
        }

        if (ct < 7) {
            #pragma unroll
            for (int q = 0; q < 4; ++q) bcur[q] = bnxt[q];
            yv0 = yn0; yv1 = yn1;
        }
    }

    // ---- row-min: cross-lane (lr) reduce once per block, then cross-wave LDS
    #pragma unroll
    for (int m = 0; m < 8; ++m)
        #pragma unroll
        for (int j = 0; j < 4; ++j) {
            float v = rowm[m][j];
            v = fminf(v, __shfl_xor(v, 1));
            v = fminf(v, __shfl_xor(v, 2));
            v = fminf(v, __shfl_xor(v, 4));
            v = fminf(v, __shfl_xor(v, 8));
            if (lr == 0) {
                const int row = m * 16 + lh * 4 + j;
                const float d2 = fmaxf(ldsX[row] + v, 0.f);
                atomicMin(&lrow[row], __float_as_uint(d2));   // LDS atomic
            }
        }
    __syncthreads();

    // ---- flush: fire-and-forget global atomics AFTER the final barrier
    if (tid < 128) atomicMin(&rmin[brow + tid], lrow[tid]);
    {
        const f32x4 cv = *(const f32x4*)&colbuf[tid * 4];
        const float4 yq = *(const float4*)&y2[bcol0 + tid * 4];
        const float d0 = fmaxf(cv[0] + yq.x, 0.f);
        const float d1 = fmaxf(cv[1] + yq.y, 0.f);
        const float d2 = fmaxf(cv[2] + yq.z, 0.f);
        const float d3 = fmaxf(cv[3] + yq.w, 0.f);
        atomicMin(&cmin[bcol0 + tid * 4 + 0], __float_as_uint(d0));
        atomicMin(&cmin[bcol0 + tid * 4 + 1], __float_as_uint(d1));
        atomicMin(&cmin[bcol0 + tid * 4 + 2], __float_as_uint(d2));
        atomicMin(&cmin[bcol0 + tid * 4 + 3], __float_as_uint(d3));
    }
}

// ---------------------------------------------------------------------------
// finalize: out = mean(sqrt(rmin)) + mean(sqrt(cmin)); 1024 thr, uint4 loads.
// ---------------------------------------------------------------------------
__global__ __launch_bounds__(1024) void ahd_finalize(
    const unsigned int* __restrict__ rmin, const unsigned int* __restrict__ cmin,
    float* __restrict__ out, int N, int M)
{
    const int tid = threadIdx.x;
    const uint4* r4 = (const uint4*)rmin;
    const uint4* c4 = (const uint4*)cmin;
    float sa = 0.f, sb = 0.f;
    for (int i = tid; i < (N >> 2); i += 1024) {
        const uint4 v = r4[i];
        sa += sqrtf(__uint_as_float(v.x)) + sqrtf(__uint_as_float(v.y))
            + sqrtf(__uint_as_float(v.z)) + sqrtf(__uint_as_float(v.w));
    }
    for (int i = tid; i < (M >> 2); i += 1024) {
        const uint4 v = c4[i];
        sb += sqrtf(__uint_as_float(v.x)) + sqrtf(__uint_as_float(v.y))
            + sqrtf(__uint_as_float(v.z)) + sqrtf(__uint_as_float(v.w));
    }
    float v = sa / (float)N + sb / (float)M;
    #pragma unroll
    for (int s = 1; s < 64; s <<= 1) v += __shfl_xor(v, s);
    __shared__ float red[16];
    if ((tid & 63) == 0) red[tid >> 6] = v;
    __syncthreads();
    if (tid == 0) {
        float t = 0.f;
        #pragma unroll
        for (int i = 0; i < 16; ++i) t += red[i];
        out[0] = t;
    }
}

extern "C" void kernel_launch(void* const* d_in, const int* in_sizes, int n_in,
                              void* d_out, int out_size, void* d_ws, size_t ws_size,
                              hipStream_t stream) {
    const float* s1 = (const float*)d_in[0];
    const float* s2 = (const float*)d_in[1];
    const int N = in_sizes[0] / 64;
    const int M = in_sizes[1] / 64;

    char* ws = (char*)d_ws;
    __hip_bfloat16* abf = (__hip_bfloat16*)ws;
    __hip_bfloat16* bbf = (__hip_bfloat16*)(ws + (size_t)N * 128);
    float* x2 = (float*)(ws + (size_t)(N + M) * 128);
    float* y2 = x2 + N;
    unsigned int* rmin = (unsigned int*)(y2 + M);
    unsigned int* cmin = rmin + N;

    const int rows = N + M;
    ahd_prep<<<(rows + 3) / 4, 256, 0, stream>>>(s1, s2, abf, bbf, x2, y2,
                                                 rmin, cmin, N, M);
    const int NRB = N / 128;            // 128 row-blocks
    const int STRIPS = M / 1024;        // 16 col-strips
    const int nwg = NRB * STRIPS;       // 2048 blocks
    ahd_gemm<<<nwg, 256, 0, stream>>>(abf, bbf, x2, y2, rmin, cmin, NRB, nwg);
    ahd_finalize<<<1, 1024, 0, stream>>>(rmin, cmin, (float*)d_out, N, M);
}